// Round 7
// baseline (576.561 us; speedup 1.0000x reference)
//
#include <hip/hip_runtime.h>

// Problem constants (fixed by setup_inputs: H=W=256, WIN=8, NCAV=2, C=256, HEADS=8)
#define NT   64
#define CDIM 256
#define NHEAD 8
#define SCALE 0.17677669529663687f   // hd^-0.5 = 1/sqrt(32)
#define PI_F 3.14159265358979f

typedef short bfrag __attribute__((ext_vector_type(8)));   // 8 bf16 (4 VGPRs)
typedef float f4    __attribute__((ext_vector_type(4)));   // MFMA C/D
typedef unsigned short us4 __attribute__((ext_vector_type(4)));
typedef unsigned short us8 __attribute__((ext_vector_type(8)));

__device__ __forceinline__ unsigned short f2bf(float f){
  unsigned u = __builtin_bit_cast(unsigned, f);
  u += 0x7FFFu + ((u >> 16) & 1u);       // round-to-nearest-even
  return (unsigned short)(u >> 16);
}
__device__ __forceinline__ unsigned pk2(float a, float b){
  return (unsigned)f2bf(a) | ((unsigned)f2bf(b) << 16);
}
__device__ __forceinline__ f4 mfma16(bfrag a, bfrag b, f4 c){
  return __builtin_amdgcn_mfma_f32_16x16x32_bf16(a, b, c, 0, 0, 0);
}
// swizzle: 64 rows x 32 16B-units/row; unit ^= row&7 -> 2-way (free)
__device__ __forceinline__ int swx(int row, int u){ return (row << 5) + (u ^ (row & 7)); }

// mfma16(A,B) -> C[A's cc-axis on quad*4+r][B's cc-axis on cc]  (proven r1).
// xpose(m0,m1): input two stacked C-frags (rows 0-15, 16-31 over same cols);
// output input-frag: lane holds col-axis=cc, row-axis(32) spread on quad*8+e.
__device__ __forceinline__ bfrag xpose(f4 m0, f4 m1, int quad, int cc){
  int P0m0 = (int)pk2(m0[0], m0[1]);
  int P1m0 = (int)pk2(m0[2], m0[3]);
  int P0m1 = (int)pk2(m1[0], m1[1]);
  int P1m1 = (int)pk2(m1[2], m1[3]);
  int srcA = ((quad & 1) << 5) + cc;
  int srcB = srcA + 16;
  int hi = quad >> 1;
  int a0 = __shfl(P0m0, srcA, 64), a1 = __shfl(P0m1, srcA, 64);
  int b0 = __shfl(P1m0, srcA, 64), b1 = __shfl(P1m1, srcA, 64);
  int c0 = __shfl(P0m0, srcB, 64), c1 = __shfl(P0m1, srcB, 64);
  int d0 = __shfl(P1m0, srcB, 64), d1 = __shfl(P1m1, srcB, 64);
  union { bfrag f; int u[4]; } r;
  r.u[0] = hi ? a1 : a0;
  r.u[1] = hi ? b1 : b0;
  r.u[2] = hi ? c1 : c0;
  r.u[3] = hi ? d1 : d0;
  return r.f;
}

// 32ch x 32tok sub-GEMM: A = wt rows [ocb,ocb+32), B = x tokens [tb,tb+32) from LDS.
// Returns two bias-added input-layout frags (token tiles tb+0..15, tb+16..31).
__device__ __forceinline__ void subgemm32(const unsigned short* __restrict__ wt,
                                          const unsigned short* lx,
                                          const float* __restrict__ bqkv,
                                          int ocb, int tb, int quad, int cc,
                                          bfrag& f0, bfrag& f1)
{
  f4 acc[2][2];
  acc[0][0] = (f4){0,0,0,0}; acc[0][1] = (f4){0,0,0,0};
  acc[1][0] = (f4){0,0,0,0}; acc[1][1] = (f4){0,0,0,0};
  #pragma unroll
  for (int ks = 0; ks < 8; ++ks){
    bfrag a0 = *(const bfrag*)(wt + (ocb +      cc)*256 + ks*32 + quad*8);
    bfrag a1 = *(const bfrag*)(wt + (ocb + 16 + cc)*256 + ks*32 + quad*8);
    bfrag b0 = *(const bfrag*)(&lx[swx(tb +      cc, ks*4 + quad)*8]);
    bfrag b1 = *(const bfrag*)(&lx[swx(tb + 16 + cc, ks*4 + quad)*8]);
    acc[0][0] = mfma16(a0, b0, acc[0][0]);
    acc[0][1] = mfma16(a0, b1, acc[0][1]);
    acc[1][0] = mfma16(a1, b0, acc[1][0]);
    acc[1][1] = mfma16(a1, b1, acc[1][1]);
  }
  #pragma unroll
  for (int mt = 0; mt < 2; ++mt)
    #pragma unroll
    for (int r = 0; r < 4; ++r){
      float bb = bqkv[ocb + mt*16 + quad*4 + r];
      acc[mt][0][r] += bb;
      acc[mt][1][r] += bb;
    }
  f0 = xpose(acc[0][0], acc[1][0], quad, cc);
  f1 = xpose(acc[0][1], acc[1][1], quad, cc);
}

// ---------------------------------------------------------------------------
// Prep (r1 version): bf16 W^T (q-scaled), rel_bias table, ego table, qkv bias
// ---------------------------------------------------------------------------
__global__ void prep_kernel(const float* __restrict__ aff,
                            const float* __restrict__ Wq,  const float* __restrict__ bq,
                            const float* __restrict__ Wkv, const float* __restrict__ bkv,
                            const float* __restrict__ Wp,
                            const float* __restrict__ relt, const float* __restrict__ egot,
                            unsigned short* __restrict__ wt, float* __restrict__ relb,
                            float* __restrict__ egob, float* __restrict__ bqkv)
{
  const int bid = blockIdx.x, tid = threadIdx.x;
  if (bid < 256) {                        // tiled weight transpose + bf16
    __shared__ float t[32][33];
    const int r0 = (bid >> 3) * 32;
    const int c0 = (bid & 7) * 32;
    const int rl = tid & 31, ch = tid >> 5;
    for (int k = 0; k < 4; ++k){
      int c = c0 + ch + k*8, r = r0 + rl;
      float v;
      if (r < 256)      v = Wq[c*256 + r] * SCALE;
      else if (r < 768) v = Wkv[c*512 + (r - 256)];
      else              v = Wp[c*256 + (r - 768)];
      t[rl][ch + k*8] = v;
    }
    __syncthreads();
    for (int k = 0; k < 4; ++k){
      int orr = ch + k*8;
      wt[(r0 + orr)*256 + c0 + rl] = f2bf(t[orr][rl]);
    }
  } else if (bid < 384) {                 // rel_bias: e = h*4096 + i*64 + j
    int e = (bid - 256)*256 + tid;
    int h = e >> 12, i = (e >> 6) & 63, j = e & 63;
    int yi = i >> 3, xi = i & 7, yj = j >> 3, xj = j & 7;
    int ridx = (yi - yj + 7)*15 + (xi - xj + 7);
    relb[e] = relt[ridx*8 + h];
  } else if (bid == 384) {                // ego bias (global max-reduce inside)
    __shared__ float red[256];
    float ex[2], ey[2];
    for (int cv = 0; cv < 2; ++cv){
      const float* A = aff + cv*6;
      ex[cv] = (A[0] + A[1])*128.0f + A[2];
      ey[cv] = (A[3] + A[4])*128.0f + A[5];
    }
    float dl = 0.0f;
    for (int p = 0; p < 4; ++p){
      int t2 = p*256 + tid;
      float cx = (float)((t2 & 31)*8 + 4), cy = (float)((t2 >> 5)*8 + 4);
      for (int cv = 0; cv < 2; ++cv){
        float dx = cx - ex[cv], dy = cy - ey[cv];
        dl = fmaxf(dl, sqrtf(dx*dx + dy*dy));
      }
    }
    red[tid] = dl; __syncthreads();
    for (int s = 128; s > 0; s >>= 1){
      if (tid < s) red[tid] = fmaxf(red[tid], red[tid + s]);
      __syncthreads();
    }
    float dmax = red[0] + 1e-6f;
    for (int p = 0; p < 4; ++p){
      int t2 = p*256 + tid;
      float cx = (float)((t2 & 31)*8 + 4), cy = (float)((t2 >> 5)*8 + 4);
      for (int cv = 0; cv < 2; ++cv){
        float dx = cx - ex[cv], dy = cy - ey[cv];
        float d = sqrtf(dx*dx + dy*dy);
        float ang = atan2f(dy, dx);
        int db = (int)(d / dmax * 3.0f);
        int ab = (int)((ang + PI_F) / (2.0f*PI_F) * 3.0f);
        int idx = db*4 + ab;
        int bw = cv*1024 + t2;
        for (int h2 = 0; h2 < 8; ++h2)
          egob[bw*8 + h2] = egot[idx*8 + h2];
      }
    }
  } else {                                // fused qkv bias (q part scaled)
    for (int j = tid; j < 768; j += 256)
      bqkv[j] = (j < 256) ? bq[j]*SCALE : bkv[j - 256];
  }
}

// ---------------------------------------------------------------------------
// K1: qkv GEMM per window (512 thr, one head per wave). Writes frag-ordered
// blobs: q/k as A-frags [unit][it4][lane][8]; v as v^T B-frags
// [unit][chunk2][nt2][lane][8]. One barrier (x staging) only.
// ---------------------------------------------------------------------------
__global__ __launch_bounds__(512, 4) void qkv_kernel(
    const float* __restrict__ x, const unsigned short* __restrict__ wt,
    const float* __restrict__ bqkv,
    unsigned short* __restrict__ qb, unsigned short* __restrict__ kb,
    unsigned short* __restrict__ vb)
{
  __shared__ unsigned short ldsX[NT*CDIM];       // 32 KiB
  const int b = blockIdx.x, tid = threadIdx.x;
  const int wv = tid >> 6, lane = tid & 63;
  const int quad = lane >> 4, cc = lane & 15;
  const int h = wv;

  const float4* xg = (const float4*)(x + (size_t)b*(NT*CDIM));
  #pragma unroll
  for (int it = 0; it < 8; ++it){
    int i4 = tid + it*512;
    float4 v = xg[i4];
    us4 pk = { f2bf(v.x), f2bf(v.y), f2bf(v.z), f2bf(v.w) };
    int row = i4 >> 6, u = (i4 & 63) >> 1, hf = i4 & 1;
    *(us4*)(&ldsX[swx(row, u)*8 + hf*4]) = pk;
  }
  __syncthreads();

  const size_t unit = (size_t)(b*8 + h);
  {
    unsigned short* qw = qb + unit*2048;
    bfrag f0, f1;
    subgemm32(wt, ldsX, bqkv, h*32, 0,  quad, cc, f0, f1);
    *(bfrag*)(qw + (0*64 + lane)*8) = f0;
    *(bfrag*)(qw + (1*64 + lane)*8) = f1;
    subgemm32(wt, ldsX, bqkv, h*32, 32, quad, cc, f0, f1);
    *(bfrag*)(qw + (2*64 + lane)*8) = f0;
    *(bfrag*)(qw + (3*64 + lane)*8) = f1;
    unsigned short* kw = kb + unit*2048;
    subgemm32(wt, ldsX, bqkv, 256 + h*32, 0,  quad, cc, f0, f1);
    *(bfrag*)(kw + (0*64 + lane)*8) = f0;
    *(bfrag*)(kw + (1*64 + lane)*8) = f1;
    subgemm32(wt, ldsX, bqkv, 256 + h*32, 32, quad, cc, f0, f1);
    *(bfrag*)(kw + (2*64 + lane)*8) = f0;
    *(bfrag*)(kw + (3*64 + lane)*8) = f1;
  }
  // v with swapped operands: C'[tok][oc] so xpose yields v^T frags [d][ktok]
  unsigned short* vw = vb + unit*2048;
  #pragma unroll
  for (int chunk = 0; chunk < 2; ++chunk){
    int tb = chunk*32;
    f4 acc[2][2];
    acc[0][0] = (f4){0,0,0,0}; acc[0][1] = (f4){0,0,0,0};
    acc[1][0] = (f4){0,0,0,0}; acc[1][1] = (f4){0,0,0,0};
    #pragma unroll
    for (int ks = 0; ks < 8; ++ks){
      bfrag x0 = *(const bfrag*)(&ldsX[swx(tb +      cc, ks*4 + quad)*8]);
      bfrag x1 = *(const bfrag*)(&ldsX[swx(tb + 16 + cc, ks*4 + quad)*8]);
      bfrag w0 = *(const bfrag*)(wt + (512 + h*32 +      cc)*256 + ks*32 + quad*8);
      bfrag w1 = *(const bfrag*)(wt + (512 + h*32 + 16 + cc)*256 + ks*32 + quad*8);
      acc[0][0] = mfma16(x0, w0, acc[0][0]);
      acc[0][1] = mfma16(x0, w1, acc[0][1]);
      acc[1][0] = mfma16(x1, w0, acc[1][0]);
      acc[1][1] = mfma16(x1, w1, acc[1][1]);
    }
    #pragma unroll
    for (int nt = 0; nt < 2; ++nt){
      float bb = bqkv[512 + h*32 + nt*16 + cc];   // bias along oc = cc axis
      #pragma unroll
      for (int r = 0; r < 4; ++r){ acc[0][nt][r] += bb; acc[1][nt][r] += bb; }
      bfrag vf = xpose(acc[0][nt], acc[1][nt], quad, cc);
      *(bfrag*)(vw + ((chunk*2 + nt)*64 + lane)*8) = vf;
    }
  }
}

// ---------------------------------------------------------------------------
// K2: attention, one wave per (window, head). ZERO LDS, ZERO barriers.
// S^T = mfma(k, q) -> per-lane softmax (2 shuffles) -> P via xpose ->
// y^T = mfma(v^T, P) -> y A-frags via xpose -> out buffer (first half of
// each window's region holds the 32 KiB y blob [qt4][h8][lane][8]).
// ---------------------------------------------------------------------------
__global__ __launch_bounds__(256, 4) void attn2_kernel(
    const unsigned short* __restrict__ qb, const unsigned short* __restrict__ kb,
    const unsigned short* __restrict__ vb, const float* __restrict__ relb,
    const float* __restrict__ egob, const float* __restrict__ wvec,
    unsigned short* __restrict__ yb)
{
  const int tid = threadIdx.x;
  const int wv = tid >> 6, lane = tid & 63;
  const int quad = lane >> 4, cc = lane & 15;
  const int unit = blockIdx.x*4 + wv;
  const int w = unit >> 3, h = unit & 7;

  float w0 = wvec[0], w1 = wvec[1];
  float wm = fmaxf(w0, w1);
  float e0 = __expf(w0 - wm), e1 = __expf(w1 - wm);
  float ws0 = e0/(e0+e1), ws1 = e1/(e0+e1);
  float ego = egob[w*8 + h];
  const float* rb = relb + h*4096;

  bfrag kf[4], vf[4];
  #pragma unroll
  for (int kt = 0; kt < 4; ++kt)
    kf[kt] = *(const bfrag*)(kb + (size_t)unit*2048 + (kt*64 + lane)*8);
  #pragma unroll
  for (int i = 0; i < 4; ++i)
    vf[i]  = *(const bfrag*)(vb + (size_t)unit*2048 + (i*64 + lane)*8);

  unsigned short* yw = yb + (size_t)w*32768;
  const f4 z = (f4){0,0,0,0};
  #pragma unroll
  for (int qt = 0; qt < 4; ++qt){
    bfrag qf = *(const bfrag*)(qb + (size_t)unit*2048 + (qt*64 + lane)*8);
    f4 SA[4];                               // S^T[ktok on kt,quad*4+r][qtok=cc]
    #pragma unroll
    for (int kt = 0; kt < 4; ++kt) SA[kt] = mfma16(kf[kt], qf, z);
    int ii = qt*16 + cc;                    // query token (per lane)
    #pragma unroll
    for (int kt = 0; kt < 4; ++kt)
      #pragma unroll
      for (int r = 0; r < 4; ++r){
        int jj = kt*16 + quad*4 + r;        // key token
        SA[kt][r] += rb[ii*64 + jj] + ego;
      }
    float m = -1e30f;
    #pragma unroll
    for (int kt = 0; kt < 4; ++kt)
      #pragma unroll
      for (int r = 0; r < 4; ++r) m = fmaxf(m, SA[kt][r]);
    m = fmaxf(m, __shfl_xor(m, 16, 64));
    m = fmaxf(m, __shfl_xor(m, 32, 64));
    float s = 0.0f;
    #pragma unroll
    for (int kt = 0; kt < 4; ++kt)
      #pragma unroll
      for (int r = 0; r < 4; ++r) s += __expf(SA[kt][r] - m);
    s += __shfl_xor(s, 16, 64);
    s += __shfl_xor(s, 32, 64);
    float Z = m + __logf(s);
    #pragma unroll
    for (int kt = 0; kt < 4; ++kt)
      #pragma unroll
      for (int r = 0; r < 4; ++r){
        float av = SA[kt][r];
        float rl = fmaxf(av, 0.0f);
        SA[kt][r] = ws0 * __expf(av - Z) + ws1 * rl * rl;
      }
    bfrag p0 = xpose(SA[0], SA[1], quad, cc);   // P A-frag, ktok chunk 0
    bfrag p1 = xpose(SA[2], SA[3], quad, cc);   // chunk 1
    f4 yT0 = mfma16(vf[0], p0, z); yT0 = mfma16(vf[2], p1, yT0);  // d 0-15
    f4 yT1 = mfma16(vf[1], p0, z); yT1 = mfma16(vf[3], p1, yT1);  // d 16-31
    bfrag yf = xpose(yT0, yT1, quad, cc);       // y A-frag [qtok=cc][d 0-31]
    *(bfrag*)(yw + ((qt*8 + h)*64 + lane)*8) = yf;
  }
}

// ---------------------------------------------------------------------------
// K3: proj per window (512 thr). Stage 32 KiB y blob -> LDS, barrier, GEMM
// vs Wp^T, write f32 out (overwrites the blob region — safe: all global
// reads complete before the barrier).
// ---------------------------------------------------------------------------
__global__ __launch_bounds__(512, 4) void proj_kernel(
    float* __restrict__ out, const unsigned short* __restrict__ wt,
    const float* __restrict__ bp)
{
  __shared__ unsigned short ldsY[16384];         // 32 KiB
  const int b = blockIdx.x, tid = threadIdx.x;
  const int wv = tid >> 6, lane = tid & 63;
  const int quad = lane >> 4, cc = lane & 15;
  const unsigned short* ys = (const unsigned short*)out + (size_t)b*32768;
  #pragma unroll
  for (int i = 0; i < 4; ++i){
    int idx = tid + i*512;                       // 2048 x 16B
    *(us8*)(&ldsY[idx*8]) = *(const us8*)(ys + idx*8);
  }
  __syncthreads();

  const int mt = wv & 3;
  const int cb = (wv >> 2)*128;
  f4 o[8];
  #pragma unroll
  for (int nt = 0; nt < 8; ++nt) o[nt] = (f4){0,0,0,0};
  #pragma unroll
  for (int ks = 0; ks < 8; ++ks){
    bfrag ay = *(const bfrag*)(&ldsY[((mt*8 + ks)*64 + lane)*8]);
    #pragma unroll
    for (int nt = 0; nt < 8; ++nt){
      bfrag bw = *(const bfrag*)(wt + (768 + cb + nt*16 + cc)*256 + ks*32 + quad*8);
      o[nt] = mfma16(ay, bw, o[nt]);
    }
  }
  float* og = out + (size_t)b*(NT*CDIM);
  #pragma unroll
  for (int nt = 0; nt < 8; ++nt){
    int col = cb + nt*16 + cc;
    float bpv = bp[col];
    #pragma unroll
    for (int r = 0; r < 4; ++r){
      int tok = mt*16 + quad*4 + r;
      og[tok*256 + col] = o[nt][r] + bpv;
    }
  }
}

// ---------------------------------------------------------------------------
// Fallback: round-1 monolithic kernel (verbatim; known-good 347 us) for the
// case ws_size < blob requirement.
// ---------------------------------------------------------------------------
#define QK_LD 40
#define HSLAB 7168
__global__ __launch_bounds__(1024, 4) void attn_mono(
    const float* __restrict__ x, const float* __restrict__ wvec,
    const float* __restrict__ bp, float* __restrict__ out,
    const unsigned short* __restrict__ wt, const float* __restrict__ relb,
    const float* __restrict__ egob, const float* __restrict__ bqkv)
{
  __shared__ unsigned short lds_x[NT*CDIM];
  __shared__ unsigned short lds_qkv[NHEAD*HSLAB];
  const int b = blockIdx.x;
  const int tid = threadIdx.x;
  const int wv = tid >> 6, lane = tid & 63;
  const int quad = lane >> 4, cc = lane & 15;
  const float4* xg = (const float4*)(x + (size_t)b*(NT*CDIM));
  for (int it = 0; it < 4; ++it){
    int i4 = tid + it*1024;
    float4 v = xg[i4];
    us4 pk = { f2bf(v.x), f2bf(v.y), f2bf(v.z), f2bf(v.w) };
    int row = i4 >> 6, u = (i4 & 63) >> 1, hf = i4 & 1;
    *(us4*)(&lds_x[swx(row, u)*8 + hf*4]) = pk;
  }
  float w0 = wvec[0], w1 = wvec[1];
  float wm = fmaxf(w0, w1);
  float e0 = __expf(w0 - wm), e1 = __expf(w1 - wm);
  float ws0 = e0/(e0+e1), ws1 = e1/(e0+e1);
  __syncthreads();
  {
    const int ob = wv*48;
    f4 acc[3][4];
    for (int mt=0;mt<3;++mt) for (int nt=0;nt<4;++nt) acc[mt][nt] = (f4){0,0,0,0};
    bfrag afr[3], nafr[3];
    for (int mt=0;mt<3;++mt)
      afr[mt] = *(const bfrag*)(wt + (ob + mt*16 + cc)*256 + quad*8);
    #pragma unroll
    for (int ks = 0; ks < 8; ++ks){
      if (ks < 7)
        for (int mt=0;mt<3;++mt)
          nafr[mt] = *(const bfrag*)(wt + (ob + mt*16 + cc)*256 + (ks+1)*32 + quad*8);
      bfrag bfr[4];
      for (int nt=0;nt<4;++nt)
        bfr[nt] = *(const bfrag*)(&lds_x[swx(nt*16 + cc, ks*4 + quad)*8]);
      for (int mt=0;mt<3;++mt)
        for (int nt=0;nt<4;++nt)
          acc[mt][nt] = mfma16(afr[mt], bfr[nt], acc[mt][nt]);
      if (ks < 7)
        for (int mt=0;mt<3;++mt) afr[mt] = nafr[mt];
    }
    for (int mt=0;mt<3;++mt){
      int oc0 = ob + mt*16 + quad*4;
      float bb0 = bqkv[oc0], bb1 = bqkv[oc0+1], bb2 = bqkv[oc0+2], bb3 = bqkv[oc0+3];
      int part = oc0 >> 8, ch = oc0 & 255;
      int h2 = ch >> 5, d0 = ch & 31;
      unsigned short* hb = &lds_qkv[h2*HSLAB];
      for (int nt=0;nt<4;++nt){
        int tok = nt*16 + cc;
        float v0 = acc[mt][nt][0] + bb0;
        float v1 = acc[mt][nt][1] + bb1;
        float v2 = acc[mt][nt][2] + bb2;
        float v3 = acc[mt][nt][3] + bb3;
        if (part < 2){
          us4 pk = { f2bf(v0), f2bf(v1), f2bf(v2), f2bf(v3) };
          *(us4*)(&hb[part*2560 + tok*QK_LD + d0]) = pk;
        } else {
          unsigned short* vs = hb + 5120;
          int tu = tok >> 3, te = tok & 7;
          vs[(d0+0)*64 + ((tu ^ ((d0+0)&7))<<3) + te] = f2bf(v0);
          vs[(d0+1)*64 + ((tu ^ ((d0+1)&7))<<3) + te] = f2bf(v1);
          vs[(d0+2)*64 + ((tu ^ ((d0+2)&7))<<3) + te] = f2bf(v2);
          vs[(d0+3)*64 + ((tu ^ ((d0+3)&7))<<3) + te] = f2bf(v3);
        }
      }
    }
  }
  __syncthreads();
  const int h = wv >> 1, half = wv & 1;
  f4 yacc[2][2];
  {
    const unsigned short* qs  = &lds_qkv[h*HSLAB];
    const unsigned short* ks_ = qs + 2560;
    const unsigned short* vts = qs + 5120;
    float ego = egob[b*8 + h];
    const float* rbp = relb + h*4096;
    bfrag bk[4];
    for (int jt=0;jt<4;++jt)
      bk[jt] = *(const bfrag*)(&ks_[(jt*16 + cc)*QK_LD + quad*8]);
    f4 S[2][4];
    for (int it=0;it<2;++it){
      bfrag aq = *(const bfrag*)(&qs[(half*32 + it*16 + cc)*QK_LD + quad*8]);
      for (int jt=0;jt<4;++jt){
        f4 zz = (f4){0,0,0,0};
        S[it][jt] = mfma16(aq, bk[jt], zz);
      }
    }
    float a[2][4][4];
    for (int it=0;it<2;++it)
      for (int jt=0;jt<4;++jt){
        int jj = jt*16 + cc;
        for (int r=0;r<4;++r){
          int ii = half*32 + it*16 + quad*4 + r;
          a[it][r][jt] = S[it][jt][r] + rbp[ii*64 + jj] + ego;
        }
      }
    float rmax[2][4], rinv[2][4];
    for (int it=0;it<2;++it)
      for (int r=0;r<4;++r){
        float m = fmaxf(fmaxf(a[it][r][0], a[it][r][1]), fmaxf(a[it][r][2], a[it][r][3]));
        for (int off=1; off<16; off<<=1) m = fmaxf(m, __shfl_xor(m, off, 64));
        float s = 0.0f;
        for (int jt=0;jt<4;++jt) s += __expf(a[it][r][jt] - m);
        for (int off=1; off<16; off<<=1) s += __shfl_xor(s, off, 64);
        rmax[it][r] = m; rinv[it][r] = 1.0f / s;
      }
    for (int it=0;it<2;++it) for (int nt=0;nt<2;++nt) yacc[it][nt] = (f4){0,0,0,0};
    unsigned short* Pw = &lds_x[wv*1024];
    for (int chunk=0; chunk<2; ++chunk){
      for (int it=0;it<2;++it)
        for (int jtl=0;jtl<2;++jtl){
          int jt = chunk*2 + jtl;
          for (int r=0;r<4;++r){
            float av = a[it][r][jt];
            float rl = fmaxf(av, 0.0f);
            float p = ws0 * __expf(av - rmax[it][r]) * rinv[it][r] + ws1 * rl * rl;
            int row = it*16 + quad*4 + r, col = jtl*16 + cc;
            Pw[row*32 + (((col>>3) ^ (row&3))<<3) + (col&7)] = f2bf(p);
          }
        }
      bfrag pa[2], pb[2];
      for (int itl=0;itl<2;++itl){
        int row = itl*16 + cc;
        pa[itl] = *(const bfrag*)(&Pw[row*32 + ((quad ^ (row&3))<<3)]);
      }
      for (int nt=0;nt<2;++nt){
        int row = nt*16 + cc;
        pb[nt] = *(const bfrag*)(&vts[row*64 + (((chunk*4 + quad) ^ (row&7))<<3)]);
      }
      for (int itl=0;itl<2;++itl)
        for (int nt=0;nt<2;++nt)
          yacc[itl][nt] = mfma16(pa[itl], pb[nt], yacc[itl][nt]);
    }
  }
  __syncthreads();
  for (int itl=0;itl<2;++itl)
    for (int nt=0;nt<2;++nt)
      for (int r=0;r<4;++r){
        int ii = half*32 + itl*16 + quad*4 + r;
        int col = h*32 + nt*16 + cc;
        lds_x[swx(ii, col>>3)*8 + (col&7)] = f2bf(yacc[itl][nt][r]);
      }
  __syncthreads();
  {
    const int mt = wv & 3;
    const int cb = (wv >> 2)*64;
    f4 o[4];
    for (int nt=0;nt<4;++nt) o[nt] = (f4){0,0,0,0};
    bfrag bw[4], nbw[4];
    for (int nt=0;nt<4;++nt)
      bw[nt] = *(const bfrag*)(wt + (768 + cb + nt*16 + cc)*256 + quad*8);
    #pragma unroll
    for (int ks=0; ks<8; ++ks){
      if (ks < 7)
        for (int nt=0;nt<4;++nt)
          nbw[nt] = *(const bfrag*)(wt + (768 + cb + nt*16 + cc)*256 + (ks+1)*32 + quad*8);
      bfrag ay = *(const bfrag*)(&lds_x[swx(mt*16 + cc, ks*4 + quad)*8]);
      for (int nt=0;nt<4;++nt)
        o[nt] = mfma16(ay, bw[nt], o[nt]);
      if (ks < 7)
        for (int nt=0;nt<4;++nt) bw[nt] = nbw[nt];
    }
    float* og = out + (size_t)b*(NT*CDIM);
    for (int nt=0;nt<4;++nt){
      int col = cb + nt*16 + cc;
      float bpv = bp[col];
      for (int r=0;r<4;++r){
        int tok = mt*16 + quad*4 + r;
        og[tok*256 + col] = o[nt][r] + bpv;
      }
    }
  }
}

extern "C" void kernel_launch(void* const* d_in, const int* in_sizes, int n_in,
                              void* d_out, int out_size, void* d_ws, size_t ws_size,
                              hipStream_t stream)
{
  const float* x    = (const float*)d_in[0];
  const float* aff  = (const float*)d_in[1];
  const float* Wq   = (const float*)d_in[2];
  const float* bq   = (const float*)d_in[3];
  const float* Wkv  = (const float*)d_in[4];
  const float* bkv  = (const float*)d_in[5];
  const float* Wp   = (const float*)d_in[6];
  const float* bp   = (const float*)d_in[7];
  const float* relt = (const float*)d_in[8];
  const float* egot = (const float*)d_in[9];
  const float* w    = (const float*)d_in[10];
  float* out = (float*)d_out;

  char* ws = (char*)d_ws;
  unsigned short* wt = (unsigned short*)ws;       // 512 KiB bf16 W^T
  float* relb = (float*)(ws + 524288);            // 128 KiB
  float* egob = (float*)(ws + 655360);            //  64 KiB
  float* bqkv = (float*)(ws + 720896);            //   3 KiB

  hipLaunchKernelGGL(prep_kernel, dim3(386), dim3(256), 0, stream,
                     aff, Wq, bq, Wkv, bkv, Wp, relt, egot, wt, relb, egob, bqkv);

  const size_t QOFF = 786432;                     // blobs start (768 KiB)
  const size_t BLOB = (size_t)16384*2048*2;       // 67,108,864 B each
  if (ws_size >= QOFF + 3*BLOB){
    unsigned short* qb = (unsigned short*)(ws + QOFF);
    unsigned short* kb = (unsigned short*)(ws + QOFF + BLOB);
    unsigned short* vb = (unsigned short*)(ws + QOFF + 2*BLOB);
    hipLaunchKernelGGL(qkv_kernel, dim3(2048), dim3(512), 0, stream,
                       x, wt, bqkv, qb, kb, vb);
    hipLaunchKernelGGL(attn2_kernel, dim3(4096), dim3(256), 0, stream,
                       qb, kb, vb, relb, egob, w, (unsigned short*)out);
    hipLaunchKernelGGL(proj_kernel, dim3(2048), dim3(512), 0, stream,
                       out, wt, bp);
  } else {
    hipLaunchKernelGGL(attn_mono, dim3(2048), dim3(1024), 0, stream,
                       x, w, bp, out, wt, relb, egob, bqkv);
  }
}